// Round 1
// baseline (397.412 us; speedup 1.0000x reference)
//
#include <hip/hip_runtime.h>

// Problem constants (fixed by setup_inputs)
#define NB 16
#define NE 8
#define NH 512
#define NW 1024
#define HW (NH * NW)            // 524288 pixels per image
#define CHUNKS 64               // blocks per image
#define TPB 256
#define PIX_PER_CHUNK (HW / CHUNKS)         // 8192
#define GROUPS (PIX_PER_CHUNK / (TPB * 4))  // 8 groups of 4 pixels per thread
#define ACC_STRIDE 40           // per-b: cnt[4], sumsq[4], sums[4][8]

// Stage 1: per-block partial statistics, atomically accumulated into acc[b][40].
// Label 0 contributes nothing (binary_label == (label>0) zeroes pred_roi), so we
// only track labels 1..4. binary_label input is therefore never read.
__global__ __launch_bounds__(TPB) void cluster_partial(
    const float* __restrict__ pred, const int* __restrict__ lab,
    float* __restrict__ acc)
{
    const int b     = blockIdx.x / CHUNKS;
    const int chunk = blockIdx.x % CHUNKS;
    const int t     = threadIdx.x;

    const float* predb = pred + (long)b * NE * HW;
    const int*   labb  = lab  + (long)b * HW;
    const int chunkbase = chunk * PIX_PER_CHUNK;

    float sums[4][NE];
    float ssq_acc[4] = {0.f, 0.f, 0.f, 0.f};
    float cnt[4]     = {0.f, 0.f, 0.f, 0.f};
#pragma unroll
    for (int l = 0; l < 4; ++l)
#pragma unroll
        for (int e = 0; e < NE; ++e) sums[l][e] = 0.f;

    for (int g = 0; g < GROUPS; ++g) {
        const int pixoff = chunkbase + ((g * TPB + t) << 2);

        const int4 l4 = *reinterpret_cast<const int4*>(labb + pixoff);
        const int labs[4] = {l4.x, l4.y, l4.z, l4.w};

        // one-hot masks for labels 1..4 (label 0 / out-of-range -> all zero)
        float m[4][4];
#pragma unroll
        for (int p = 0; p < 4; ++p)
#pragma unroll
            for (int l = 0; l < 4; ++l)
                m[p][l] = (labs[p] == l + 1) ? 1.0f : 0.0f;

        float ssq[4] = {0.f, 0.f, 0.f, 0.f};
#pragma unroll
        for (int e = 0; e < NE; ++e) {
            const float4 v =
                *reinterpret_cast<const float4*>(predb + (long)e * HW + pixoff);
            const float vv[4] = {v.x, v.y, v.z, v.w};
#pragma unroll
            for (int p = 0; p < 4; ++p) {
                ssq[p] = fmaf(vv[p], vv[p], ssq[p]);
#pragma unroll
                for (int l = 0; l < 4; ++l)
                    sums[l][e] = fmaf(m[p][l], vv[p], sums[l][e]);
            }
        }
#pragma unroll
        for (int p = 0; p < 4; ++p)
#pragma unroll
            for (int l = 0; l < 4; ++l) {
                ssq_acc[l] = fmaf(m[p][l], ssq[p], ssq_acc[l]);
                cnt[l] += m[p][l];
            }
    }

    // Pack 40 per-thread partials; wave(64)-level shuffle reduction.
    float vals[ACC_STRIDE];
#pragma unroll
    for (int l = 0; l < 4; ++l) {
        vals[l]     = cnt[l];
        vals[4 + l] = ssq_acc[l];
#pragma unroll
        for (int e = 0; e < NE; ++e) vals[8 + l * NE + e] = sums[l][e];
    }
#pragma unroll
    for (int i = 0; i < ACC_STRIDE; ++i) {
        float v = vals[i];
        v += __shfl_down(v, 32);
        v += __shfl_down(v, 16);
        v += __shfl_down(v, 8);
        v += __shfl_down(v, 4);
        v += __shfl_down(v, 2);
        v += __shfl_down(v, 1);
        vals[i] = v;
    }

    __shared__ float red[TPB / 64][ACC_STRIDE];
    const int wave = t >> 6;
    const int lane = t & 63;
    if (lane == 0) {
#pragma unroll
        for (int i = 0; i < ACC_STRIDE; ++i) red[wave][i] = vals[i];
    }
    __syncthreads();
    if (t < ACC_STRIDE) {
        float s = red[0][t] + red[1][t] + red[2][t] + red[3][t];
        atomicAdd(&acc[b * ACC_STRIDE + t], s);
    }
}

// Stage 2: tiny finalize — one thread per batch image, wave-reduce, write scalar.
__global__ __launch_bounds__(64) void cluster_finalize(
    const float* __restrict__ acc, float* __restrict__ out)
{
    const int t = threadIdx.x;
    float Lb = 0.f;
    if (t < NB) {
        const float* a = acc + t * ACC_STRIDE;
        float mu[4][NE];   // cluster means for labels 0..3 (mu_d); mu[0] == 0
#pragma unroll
        for (int e = 0; e < NE; ++e) mu[0][e] = 0.f;

        float Lvar = 0.f;
#pragma unroll
        for (int l = 1; l <= 4; ++l) {
            const float c   = a[l - 1];
            const float ssq = a[4 + (l - 1)];
            float mloc[NE];
            float musq = 0.f;
#pragma unroll
            for (int e = 0; e < NE; ++e) {
                mloc[e] = a[8 + (l - 1) * NE + e] / c;
                musq = fmaf(mloc[e], mloc[e], musq);
            }
            const float frob = ssq - c * musq;
            const float n = (frob > 0.f) ? sqrtf(frob) : 0.f;
            const float dv = n - 0.5f;               // DELTA_V = 0.5
            Lvar += (n > 0.5f) ? dv * dv : 0.f;
            if (l < 4) {
#pragma unroll
                for (int e = 0; e < NE; ++e) mu[l][e] = mloc[e];
            }
        }
        Lvar *= 0.25f;  // / C

        float Ldist = 0.f;
#pragma unroll
        for (int i = 0; i < 4; ++i)
#pragma unroll
            for (int j = i + 1; j < 4; ++j) {
                float dsq = 0.f;
#pragma unroll
                for (int e = 0; e < NE; ++e) {
                    const float d = mu[i][e] - mu[j][e];
                    dsq = fmaf(d, d, dsq);
                }
                float h;
                if (dsq > 0.f) {
                    const float d = sqrtf(dsq);
                    float r = 3.0f - d;              // DELTA_D = 3.0
                    r = (r > 0.f) ? r : 0.f;
                    h = r * r;
                } else {
                    h = 9.0f;                        // DELTA_D^2
                }
                Ldist += 2.0f * h;                   // both (i,j) and (j,i)
            }

        Lb = (Lvar + Ldist) * (1.0f / NB);           // mean over B of both terms
    }
    Lb += __shfl_down(Lb, 32);
    Lb += __shfl_down(Lb, 16);
    Lb += __shfl_down(Lb, 8);
    Lb += __shfl_down(Lb, 4);
    Lb += __shfl_down(Lb, 2);
    Lb += __shfl_down(Lb, 1);
    if (t == 0) out[0] = Lb;
}

extern "C" void kernel_launch(void* const* d_in, const int* in_sizes, int n_in,
                              void* d_out, int out_size, void* d_ws, size_t ws_size,
                              hipStream_t stream) {
    const float* pred = (const float*)d_in[0];
    // d_in[1] = binary_label: unused — it is exactly (instance_label > 0).
    const int* lab = (const int*)d_in[2];
    float* out = (float*)d_out;
    float* acc = (float*)d_ws;   // NB*40 floats = 2560 B, ws is poisoned -> zero it

    hipMemsetAsync(acc, 0, NB * ACC_STRIDE * sizeof(float), stream);
    cluster_partial<<<NB * CHUNKS, TPB, 0, stream>>>(pred, lab, acc);
    cluster_finalize<<<1, 64, 0, stream>>>(acc, out);
}

// Round 2
// 394.348 us; speedup vs baseline: 1.0078x; 1.0078x over previous
//
#include <hip/hip_runtime.h>

// Problem constants (fixed by setup_inputs)
#define NB 16
#define NE 8
#define NH 512
#define NW 1024
#define HW (NH * NW)            // 524288 pixels per image
#define CHUNKS 128              // blocks per image (2048 total, 8 blocks/CU)
#define TPB 256
#define PIX_PER_CHUNK (HW / CHUNKS)         // 4096
#define GROUPS (PIX_PER_CHUNK / (TPB * 4))  // 4 groups of 4 pixels per thread
#define ACC_STRIDE 40           // per-b: cnt[4], sumsq[4], sums[4][8]

// Stage 1: per-block partial statistics, atomically accumulated into acc[b][40].
// Label 0 contributes nothing (binary_label == (label>0) zeroes pred_roi), so we
// only track labels 1..4. binary_label input is therefore never read.
// g-loop is software-pipelined: group g+1's 9 loads (1 int4 + 8 float4) issue
// before group g's FMA work, so waves don't stall on vmcnt every iteration.
__global__ __launch_bounds__(TPB) void cluster_partial(
    const float* __restrict__ pred, const int* __restrict__ lab,
    float* __restrict__ acc)
{
    const int b     = blockIdx.x / CHUNKS;
    const int chunk = blockIdx.x % CHUNKS;
    const int t     = threadIdx.x;

    const float* predb = pred + (long)b * NE * HW;
    const int*   labb  = lab  + (long)b * HW;
    const int base0 = chunk * PIX_PER_CHUNK + (t << 2);

    float sums[4][NE];
    float ssq_acc[4] = {0.f, 0.f, 0.f, 0.f};
    float cnt[4]     = {0.f, 0.f, 0.f, 0.f};
#pragma unroll
    for (int l = 0; l < 4; ++l)
#pragma unroll
        for (int e = 0; e < NE; ++e) sums[l][e] = 0.f;

    // prime the pipeline: group 0 loads
    int4   l4 = *reinterpret_cast<const int4*>(labb + base0);
    float4 v[NE];
#pragma unroll
    for (int e = 0; e < NE; ++e)
        v[e] = *reinterpret_cast<const float4*>(predb + (long)e * HW + base0);

#pragma unroll
    for (int g = 0; g < GROUPS; ++g) {
        // prefetch group g+1 while computing group g
        int4   l4n = l4;
        float4 vn[NE];
#pragma unroll
        for (int e = 0; e < NE; ++e) vn[e] = v[e];
        if (g + 1 < GROUPS) {
            const int off = base0 + (g + 1) * (TPB * 4);
            l4n = *reinterpret_cast<const int4*>(labb + off);
#pragma unroll
            for (int e = 0; e < NE; ++e)
                vn[e] = *reinterpret_cast<const float4*>(predb + (long)e * HW + off);
        }

        const int labs[4] = {l4.x, l4.y, l4.z, l4.w};

        // one-hot masks for labels 1..4 (label 0 -> all zero)
        float m[4][4];
#pragma unroll
        for (int p = 0; p < 4; ++p)
#pragma unroll
            for (int l = 0; l < 4; ++l)
                m[p][l] = (labs[p] == l + 1) ? 1.0f : 0.0f;

        float ssq[4] = {0.f, 0.f, 0.f, 0.f};
#pragma unroll
        for (int e = 0; e < NE; ++e) {
            const float vv[4] = {v[e].x, v[e].y, v[e].z, v[e].w};
#pragma unroll
            for (int p = 0; p < 4; ++p) {
                ssq[p] = fmaf(vv[p], vv[p], ssq[p]);
#pragma unroll
                for (int l = 0; l < 4; ++l)
                    sums[l][e] = fmaf(m[p][l], vv[p], sums[l][e]);
            }
        }
#pragma unroll
        for (int p = 0; p < 4; ++p)
#pragma unroll
            for (int l = 0; l < 4; ++l) {
                ssq_acc[l] = fmaf(m[p][l], ssq[p], ssq_acc[l]);
                cnt[l] += m[p][l];
            }

        l4 = l4n;
#pragma unroll
        for (int e = 0; e < NE; ++e) v[e] = vn[e];
    }

    // Pack 40 per-thread partials; wave(64)-level shuffle reduction.
    float vals[ACC_STRIDE];
#pragma unroll
    for (int l = 0; l < 4; ++l) {
        vals[l]     = cnt[l];
        vals[4 + l] = ssq_acc[l];
#pragma unroll
        for (int e = 0; e < NE; ++e) vals[8 + l * NE + e] = sums[l][e];
    }
#pragma unroll
    for (int i = 0; i < ACC_STRIDE; ++i) {
        float vv = vals[i];
        vv += __shfl_down(vv, 32);
        vv += __shfl_down(vv, 16);
        vv += __shfl_down(vv, 8);
        vv += __shfl_down(vv, 4);
        vv += __shfl_down(vv, 2);
        vv += __shfl_down(vv, 1);
        vals[i] = vv;
    }

    __shared__ float red[TPB / 64][ACC_STRIDE];
    const int wave = t >> 6;
    const int lane = t & 63;
    if (lane == 0) {
#pragma unroll
        for (int i = 0; i < ACC_STRIDE; ++i) red[wave][i] = vals[i];
    }
    __syncthreads();
    if (t < ACC_STRIDE) {
        float s = red[0][t] + red[1][t] + red[2][t] + red[3][t];
        atomicAdd(&acc[b * ACC_STRIDE + t], s);
    }
}

// Stage 2: tiny finalize — one thread per batch image, wave-reduce, write scalar.
__global__ __launch_bounds__(64) void cluster_finalize(
    const float* __restrict__ acc, float* __restrict__ out)
{
    const int t = threadIdx.x;
    float Lb = 0.f;
    if (t < NB) {
        const float* a = acc + t * ACC_STRIDE;
        float mu[4][NE];   // cluster means for labels 0..3 (mu_d); mu[0] == 0
#pragma unroll
        for (int e = 0; e < NE; ++e) mu[0][e] = 0.f;

        float Lvar = 0.f;
#pragma unroll
        for (int l = 1; l <= 4; ++l) {
            const float c   = a[l - 1];
            const float ssq = a[4 + (l - 1)];
            float mloc[NE];
            float musq = 0.f;
#pragma unroll
            for (int e = 0; e < NE; ++e) {
                mloc[e] = a[8 + (l - 1) * NE + e] / c;
                musq = fmaf(mloc[e], mloc[e], musq);
            }
            const float frob = ssq - c * musq;
            const float n = (frob > 0.f) ? sqrtf(frob) : 0.f;
            const float dv = n - 0.5f;               // DELTA_V = 0.5
            Lvar += (n > 0.5f) ? dv * dv : 0.f;
            if (l < 4) {
#pragma unroll
                for (int e = 0; e < NE; ++e) mu[l][e] = mloc[e];
            }
        }
        Lvar *= 0.25f;  // / C

        float Ldist = 0.f;
#pragma unroll
        for (int i = 0; i < 4; ++i)
#pragma unroll
            for (int j = i + 1; j < 4; ++j) {
                float dsq = 0.f;
#pragma unroll
                for (int e = 0; e < NE; ++e) {
                    const float d = mu[i][e] - mu[j][e];
                    dsq = fmaf(d, d, dsq);
                }
                float h;
                if (dsq > 0.f) {
                    const float d = sqrtf(dsq);
                    float r = 3.0f - d;              // DELTA_D = 3.0
                    r = (r > 0.f) ? r : 0.f;
                    h = r * r;
                } else {
                    h = 9.0f;                        // DELTA_D^2
                }
                Ldist += 2.0f * h;                   // both (i,j) and (j,i)
            }

        Lb = (Lvar + Ldist) * (1.0f / NB);           // mean over B of both terms
    }
    Lb += __shfl_down(Lb, 32);
    Lb += __shfl_down(Lb, 16);
    Lb += __shfl_down(Lb, 8);
    Lb += __shfl_down(Lb, 4);
    Lb += __shfl_down(Lb, 2);
    Lb += __shfl_down(Lb, 1);
    if (t == 0) out[0] = Lb;
}

extern "C" void kernel_launch(void* const* d_in, const int* in_sizes, int n_in,
                              void* d_out, int out_size, void* d_ws, size_t ws_size,
                              hipStream_t stream) {
    const float* pred = (const float*)d_in[0];
    // d_in[1] = binary_label: unused — it is exactly (instance_label > 0).
    const int* lab = (const int*)d_in[2];
    float* out = (float*)d_out;
    float* acc = (float*)d_ws;   // NB*40 floats = 2560 B, ws is poisoned -> zero it

    hipMemsetAsync(acc, 0, NB * ACC_STRIDE * sizeof(float), stream);
    cluster_partial<<<NB * CHUNKS, TPB, 0, stream>>>(pred, lab, acc);
    cluster_finalize<<<1, 64, 0, stream>>>(acc, out);
}